// Round 16
// baseline (265.709 us; speedup 1.0000x reference)
//
#include <hip/hip_runtime.h>

// ---------------------------------------------------------------------------
// GCN forward, round 11: launch consolidation + packed-shfl agg.
// R10 = 182us best; top-5 all harness fills, no single hot kernel left.
// -> fuse pool+head (k_phead, 1 block/graph, binary-search ranges);
//    fuse castw into k_hist; pack (bf16(w)<<16|src) so agg does 1 shfl/edge.
// 13 -> 9 launches.
// ---------------------------------------------------------------------------

#define NB 256    // scatter blocks
#define NBK 256   // buckets (dst>>8; requires n <= 65536)

typedef __attribute__((ext_vector_type(8))) short bf16x8;
typedef __attribute__((ext_vector_type(4))) float f32x4;
typedef __attribute__((ext_vector_type(2))) float f32x2;

__device__ inline unsigned short f2bf(float f) {
    union { float f; unsigned int u; } c; c.f = f;
    unsigned int u = c.u + (0x7fffu + ((c.u >> 16) & 1u));  // RNE
    return (unsigned short)(u >> 16);
}
__device__ inline float bf2f(unsigned short b) {
    union { unsigned int u; float f; } c; c.u = ((unsigned int)b) << 16;
    return c.f;
}
__device__ inline float asf(unsigned int u) {
    union { unsigned int u; float f; } c; c.u = u; return c.f;
}

// Software OCP e4m3fn encode/decode (fallback only).
__device__ inline unsigned char f2fp8_sw(float f) {
    union { float f; unsigned int u; } c; c.f = f;
    unsigned int s = (c.u >> 24) & 0x80u;
    unsigned int au = c.u & 0x7FFFFFFFu;
    if (au >= 0x3C800000u) {
        if (au > 0x43E00000u) au = 0x43E00000u;
        unsigned int r = au + 0x000FFFFFu + ((au >> 20) & 1u);
        unsigned int e8 = (r >> 23) - 120u;
        unsigned int m8 = (r >> 20) & 7u;
        return (unsigned char)(s | (e8 << 3) | m8);
    }
    float av = c.f < 0.f ? -c.f : c.f;
    unsigned int M = (unsigned int)(av * 512.0f + 0.5f);
    return (unsigned char)(s | M);
}
__device__ inline float fp82f_sw(unsigned int cbyte) {
    unsigned int E = (cbyte >> 3) & 0xFu, M = cbyte & 7u;
    union { unsigned int u; float f; } v;
    v.u = ((E + 120u) << 23) | (M << 20);
    float r = E ? v.f : (float)M * 0.001953125f;
    return (cbyte & 0x80u) ? -r : r;
}

// Decode 2 packed fp8 from low (HI=false) or high (HI=true) 16 bits of u.
template <bool HI>
__device__ inline f32x2 fp8x2_f32(unsigned int u) {
#if __has_builtin(__builtin_amdgcn_cvt_pk_f32_fp8)
    return __builtin_amdgcn_cvt_pk_f32_fp8(u, HI);
#else
    unsigned int w = HI ? (u >> 16) : u;
    f32x2 r; r[0] = fp82f_sw(w & 0xFFu); r[1] = fp82f_sw((w >> 8) & 0xFFu);
    return r;
#endif
}
__device__ inline unsigned char f2fp8(float f) {
#if __has_builtin(__builtin_amdgcn_cvt_pk_fp8_f32)
    return (unsigned char)(__builtin_amdgcn_cvt_pk_fp8_f32(f, f, 0, false) & 0xFFu);
#else
    return f2fp8_sw(f);
#endif
}

// kA: per-block bucket histogram; blocks 0..127 also transpose-cast W1/W2.
__global__ __launch_bounds__(256) void k_hist(const int* __restrict__ dst,
                                              int* __restrict__ hist,
                                              const float* __restrict__ W1,
                                              const float* __restrict__ W2,
                                              unsigned short* __restrict__ Wt1,
                                              unsigned short* __restrict__ Wt2,
                                              int ne, int chunk) {
    __shared__ int h[NBK];
    int t = threadIdx.x, b = blockIdx.x;
    h[t] = 0;
    int gid = b * 256 + t;
    if (b < 64) {                       // Wt1[i] = bf16(W1[kk][nn])
        int i = gid, nn = i >> 7, kk = i & 127;
        Wt1[i] = f2bf(W1[kk * 128 + nn]);
    } else if (b < 128) {
        int i = gid - 16384, nn = i >> 7, kk = i & 127;
        Wt2[i] = f2bf(W2[kk * 128 + nn]);
    }
    __syncthreads();
    int e0 = b * chunk, e1 = min(e0 + chunk, ne);
    for (int e = e0 + t; e < e1; e += 256) atomicAdd(&h[dst[e] >> 8], 1);
    __syncthreads();
    hist[b * NBK + t] = h[t];
}

// kB: single block; thread j owns bucket j. Column-scan over blocks ->
// per-(block,bucket) base (in place), bucket starts, row_start[n] sentinel.
__global__ __launch_bounds__(256) void k_scanb(int* __restrict__ hist,
                                               int* __restrict__ bstart,
                                               int* __restrict__ row_start,
                                               int n, int ne) {
    __shared__ int ps[256];
    int j = threadIdx.x;
    int run = 0;
    for (int i = 0; i < NB; ++i) {
        int t = hist[i * NBK + j];
        hist[i * NBK + j] = run;
        run += t;
    }
    ps[j] = run;
    __syncthreads();
    for (int off = 1; off < 256; off <<= 1) {
        int v = (j >= off) ? ps[j - off] : 0;
        __syncthreads();
        ps[j] += v;
        __syncthreads();
    }
    int excl = ps[j] - run;
    bstart[j] = excl;
    if (j == 255) bstart[256] = ps[255];
    if (j == 0) row_start[n] = ne;
    for (int i = 0; i < NB; ++i) hist[i * NBK + j] += excl;
}

// kC: scatter edges into block-private bucket slices. Pack (dst&255)<<24|src.
__global__ __launch_bounds__(256) void k_scat(const int* __restrict__ src,
                                              const int* __restrict__ dst,
                                              const int* __restrict__ hist,
                                              unsigned int* __restrict__ ebuf,
                                              int ne, int chunk) {
    __shared__ int cur[NBK];
    int t = threadIdx.x, b = blockIdx.x;
    cur[t] = hist[b * NBK + t];
    __syncthreads();
    int e0 = b * chunk, e1 = min(e0 + chunk, ne);
    for (int e = e0 + t; e < e1; e += 256) {
        int d = dst[e];
        int p = atomicAdd(&cur[d >> 8], 1);
        ebuf[p] = ((unsigned int)(d & 255) << 24) | (unsigned int)src[e];
    }
}

// kD: one block per bucket: LDS counting sort -> csr, row_start, dinv.
__global__ __launch_bounds__(256) void k_bsort(const unsigned int* __restrict__ ebuf,
                                               const int* __restrict__ bstart,
                                               int* __restrict__ csr,
                                               int* __restrict__ row_start,
                                               float* __restrict__ dinv,
                                               int n) {
    __shared__ int h[NBK];
    __shared__ int sc[NBK];
    int j = threadIdx.x, b = blockIdx.x;
    int s0 = bstart[b], s1 = bstart[b + 1];
    h[j] = 0;
    __syncthreads();
    for (int e = s0 + j; e < s1; e += 256) atomicAdd(&h[ebuf[e] >> 24], 1);
    __syncthreads();
    sc[j] = h[j];
    __syncthreads();
    for (int off = 1; off < 256; off <<= 1) {
        int v = (j >= off) ? sc[j - off] : 0;
        __syncthreads();
        sc[j] += v;
        __syncthreads();
    }
    int excl = sc[j] - h[j];
    int id = b * 256 + j;
    int deg = h[j];
    if (id < n) {
        row_start[id] = s0 + excl;
        dinv[id] = rsqrtf((float)deg + 1.0f);
    }
    __syncthreads();
    h[j] = excl;
    __syncthreads();
    for (int e = s0 + j; e < s1; e += 256) {
        unsigned int pk = ebuf[e];
        int p = atomicAdd(&h[pk >> 24], 1);
        csr[s0 + p] = (int)(pk & 0x00FFFFFFu);
    }
}

// Y[M x 128](fp8) = X[M x 128] @ W (Wt = W^T bf16 [128][128]).
// F32IN: X f32 (in-register convert); else bf16. 4 waves, 64 rows/block.
template <bool F32IN>
__global__ __launch_bounds__(256) void k_gemm_mfma(const void* __restrict__ Xin,
                                                   const short* __restrict__ Wt,
                                                   unsigned char* __restrict__ Y8,
                                                   int n_rows) {
    int wid = threadIdx.x >> 6;
    int lane = threadIdx.x & 63;
    int r = lane & 15, q = lane >> 4;
    int m0 = blockIdx.x * 64;
    int n0 = wid * 32;

    bf16x8 bfr[2][4];
#pragma unroll
    for (int nt = 0; nt < 2; ++nt)
#pragma unroll
        for (int ks = 0; ks < 4; ++ks)
            bfr[nt][ks] = *(const bf16x8*)(Wt + (size_t)(n0 + nt * 16 + r) * 128 +
                                           ks * 32 + q * 8);

#pragma unroll
    for (int rt = 0; rt < 4; ++rt) {
        int row = m0 + rt * 16 + r;
        int rl = min(row, n_rows - 1);
        f32x4 acc0 = {0.f, 0.f, 0.f, 0.f};
        f32x4 acc1 = {0.f, 0.f, 0.f, 0.f};
#pragma unroll
        for (int ks = 0; ks < 4; ++ks) {
            bf16x8 a;
            if constexpr (F32IN) {
                const float* xr = (const float*)Xin + (size_t)rl * 128 + ks * 32 + q * 8;
                float4 f0 = *(const float4*)xr;
                float4 f1 = *(const float4*)(xr + 4);
                a[0] = (short)f2bf(f0.x); a[1] = (short)f2bf(f0.y);
                a[2] = (short)f2bf(f0.z); a[3] = (short)f2bf(f0.w);
                a[4] = (short)f2bf(f1.x); a[5] = (short)f2bf(f1.y);
                a[6] = (short)f2bf(f1.z); a[7] = (short)f2bf(f1.w);
            } else {
                a = *(const bf16x8*)((const short*)Xin + (size_t)rl * 128 + ks * 32 + q * 8);
            }
            acc0 = __builtin_amdgcn_mfma_f32_16x16x32_bf16(a, bfr[0][ks], acc0, 0, 0, 0);
            acc1 = __builtin_amdgcn_mfma_f32_16x16x32_bf16(a, bfr[1][ks], acc1, 0, 0, 0);
        }
#pragma unroll
        for (int v = 0; v < 4; ++v) {
            int orow = m0 + rt * 16 + q * 4 + v;
            if (orow < n_rows) {
                Y8[(size_t)orow * 128 + n0 + r]      = f2fp8(acc0[v]);
                Y8[(size_t)orow * 128 + n0 + 16 + r] = f2fp8(acc1[v]);
            }
        }
    }
}

// out[d][:] = bf16( relu( sum_e h[src]*w_e + h[d]*di^2 + bias ) )
// h fp8 [n][128]; one wave/node; half-wave dword gather (R10 structure).
// Lane pre-packs (bf16(w)<<16 | src) -> ONE shfl per edge in the hot loop.
__global__ __launch_bounds__(256) void k_agg(const unsigned char* __restrict__ h8,
                                             const float* __restrict__ dinv,
                                             const int* __restrict__ csr,
                                             const int* __restrict__ row_start,
                                             const float* __restrict__ bias,
                                             unsigned short* __restrict__ out,
                                             int n) {
    int node = blockIdx.x * 4 + (threadIdx.x >> 6);
    if (node >= n) return;
    int lane = threadIdx.x & 63;
    int s = lane >> 5, fi = lane & 31;  // half, feature-dword index
    const unsigned int* hp = (const unsigned int*)h8;  // [n][32] dwords

    float di = dinv[node];
    float selfw = (s == 0) ? di * di : 0.0f;
    unsigned int hu = hp[(size_t)node * 32 + fi];
    f32x2 p0 = fp8x2_f32<false>(hu);
    f32x2 p1 = fp8x2_f32<true>(hu);
    float a0 = p0[0] * selfw, a1 = p0[1] * selfw;
    float a2 = p1[0] * selfw, a3 = p1[1] * selfw;

    int beg = row_start[node];
    int end = row_start[node + 1];
    int deg = end - beg;

    int mysrc = (lane < deg) ? csr[beg + lane] : 0;
    float myw = ((lane < deg) ? dinv[mysrc] : 0.0f) * di;
    // pack: bf16 weight in high 16, src id (<65536) in low 16
    unsigned int mypk = ((unsigned int)f2bf(myw) << 16) | (unsigned int)(mysrc & 0xFFFF);

    int m = min(deg, 64);
    int e = 0;
    for (; e + 8 <= m; e += 8) {  // halves s=0/1 -> edges e+s, e+2+s, ...
        unsigned int k0 = __shfl(mypk, e + s);
        unsigned int k1 = __shfl(mypk, e + 2 + s);
        unsigned int k2 = __shfl(mypk, e + 4 + s);
        unsigned int k3 = __shfl(mypk, e + 6 + s);
        unsigned int u0 = hp[(size_t)(k0 & 0xFFFFu) * 32 + fi];
        unsigned int u1 = hp[(size_t)(k1 & 0xFFFFu) * 32 + fi];
        unsigned int u2 = hp[(size_t)(k2 & 0xFFFFu) * 32 + fi];
        unsigned int u3 = hp[(size_t)(k3 & 0xFFFFu) * 32 + fi];
        float w0 = asf(k0 & 0xFFFF0000u);
        float w1 = asf(k1 & 0xFFFF0000u);
        float w2 = asf(k2 & 0xFFFF0000u);
        float w3 = asf(k3 & 0xFFFF0000u);
        f32x2 v;
        v = fp8x2_f32<false>(u0); a0 += v[0] * w0; a1 += v[1] * w0;
        v = fp8x2_f32<true>(u0);  a2 += v[0] * w0; a3 += v[1] * w0;
        v = fp8x2_f32<false>(u1); a0 += v[0] * w1; a1 += v[1] * w1;
        v = fp8x2_f32<true>(u1);  a2 += v[0] * w1; a3 += v[1] * w1;
        v = fp8x2_f32<false>(u2); a0 += v[0] * w2; a1 += v[1] * w2;
        v = fp8x2_f32<true>(u2);  a2 += v[0] * w2; a3 += v[1] * w2;
        v = fp8x2_f32<false>(u3); a0 += v[0] * w3; a1 += v[1] * w3;
        v = fp8x2_f32<true>(u3);  a2 += v[0] * w3; a3 += v[1] * w3;
    }
    for (; e < m; e += 2) {  // guarded tail, 2 edges/iter
        int idx = e + s;
        unsigned int k = __shfl(mypk, idx & 63);
        float w = asf(k & 0xFFFF0000u);
        if (idx >= m) w = 0.0f;
        unsigned int u = hp[(size_t)(k & 0xFFFFu) * 32 + fi];
        f32x2 v;
        v = fp8x2_f32<false>(u); a0 += v[0] * w; a1 += v[1] * w;
        v = fp8x2_f32<true>(u);  a2 += v[0] * w; a3 += v[1] * w;
    }
    if (s == 0) {  // rare deg>64 overflow: half 0 serial
        for (int j = beg + 64; j < end; ++j) {
            int sx = csr[j];
            float w = dinv[sx] * di;
            unsigned int u = hp[(size_t)sx * 32 + fi];
            f32x2 v;
            v = fp8x2_f32<false>(u); a0 += v[0] * w; a1 += v[1] * w;
            v = fp8x2_f32<true>(u);  a2 += v[0] * w; a3 += v[1] * w;
        }
    }

    // cross-half reduce
    a0 += __shfl_xor(a0, 32);
    a1 += __shfl_xor(a1, 32);
    a2 += __shfl_xor(a2, 32);
    a3 += __shfl_xor(a3, 32);

    if (s == 0) {
        float4 bv = ((const float4*)bias)[fi];
        float o0 = fmaxf(a0 + bv.x, 0.0f);
        float o1 = fmaxf(a1 + bv.y, 0.0f);
        float o2 = fmaxf(a2 + bv.z, 0.0f);
        float o3 = fmaxf(a3 + bv.w, 0.0f);
        uint2 pk;
        pk.x = (unsigned int)f2bf(o0) | ((unsigned int)f2bf(o1) << 16);
        pk.y = (unsigned int)f2bf(o2) | ((unsigned int)f2bf(o3) << 16);
        *(uint2*)(out + (size_t)node * 128 + fi * 4) = pk;
    }
}

// Fused mean-pool + MLP head: one block (256 thr) per graph. batch sorted ->
// binary-search node range; stream rows (2/iter); head inline.
__global__ __launch_bounds__(256) void k_phead(const unsigned short* __restrict__ h,
                                               const int* __restrict__ batch,
                                               const float* __restrict__ Wh1,
                                               const float* __restrict__ bh1,
                                               const float* __restrict__ Wh2,
                                               const float* __restrict__ bh2,
                                               float* __restrict__ out, int n) {
    int g = blockIdx.x;
    int t = threadIdx.x;
    int d = t & 127, half = t >> 7;

    int lo, hi;
    { int a = 0, b = n; while (a < b) { int m = (a + b) >> 1; if (batch[m] < g) a = m + 1; else b = m; } lo = a; }
    { int a = lo, b = n; while (a < b) { int m = (a + b) >> 1; if (batch[m] < g + 1) a = m + 1; else b = m; } hi = a; }

    float acc = 0.f;
    for (int i = lo + half; i < hi; i += 2)
        acc += bf2f(h[(size_t)i * 128 + d]);

    __shared__ float red[256];
    __shared__ float sp[128];
    red[t] = acc;
    __syncthreads();
    if (t < 128) {
        float c = fmaxf((float)(hi - lo), 1.0f);
        sp[t] = (red[t] + red[t + 128]) / c;
    }
    __syncthreads();

    float z = 0.f;
    if (t < 128) {
        float a2 = bh1[t];
        for (int k = 0; k < 128; ++k) a2 += sp[k] * Wh1[k * 128 + t];
        z = fmaxf(a2, 0.f) * Wh2[t];
    }
    red[t] = (t < 128) ? z : 0.f;
    __syncthreads();
    for (int off = 64; off > 0; off >>= 1) {
        if (t < off) red[t] += red[t + off];
        __syncthreads();
    }
    if (t == 0) out[g] = 1.f / (1.f + expf(-(red[0] + bh2[0])));
}

extern "C" void kernel_launch(void* const* d_in, const int* in_sizes, int n_in,
                              void* d_out, int out_size, void* d_ws,
                              size_t ws_size, hipStream_t stream) {
    const float* x    = (const float*)d_in[0];
    const int*   ei   = (const int*)d_in[1];
    const int*   batch= (const int*)d_in[2];
    const float* W1   = (const float*)d_in[3];
    const float* b1   = (const float*)d_in[4];
    const float* W2   = (const float*)d_in[5];
    const float* b2   = (const float*)d_in[6];
    const float* Wh1  = (const float*)d_in[7];
    const float* bh1  = (const float*)d_in[8];
    const float* Wh2  = (const float*)d_in[9];
    const float* bh2  = (const float*)d_in[10];
    float* out = (float*)d_out;

    const int n  = in_sizes[0] / 128;  // 50000
    const int ne = in_sizes[1] / 2;    // 800000
    const int* src = ei;
    const int* dst = ei + ne;

    char* p = (char*)d_ws;
    int* hist      = (int*)p;  p += (size_t)NB * NBK * 4;
    int* bstart    = (int*)p;  p += 257 * 4;
    int* row_start = (int*)p;  p += (size_t)(n + 1) * 4;
    float* dinv    = (float*)p; p += (size_t)n * 4;
    unsigned int* ebuf = (unsigned int*)p; p += (size_t)ne * 4;
    int* csr       = (int*)p;  p += (size_t)ne * 4;
    p = (char*)(((uintptr_t)p + 15) & ~(uintptr_t)15);
    unsigned short* Wt1 = (unsigned short*)p; p += 128 * 128 * 2;
    unsigned short* Wt2 = (unsigned short*)p; p += 128 * 128 * 2;
    unsigned char* h8   = (unsigned char*)p; p += (size_t)n * 128;
    p = (char*)(((uintptr_t)p + 15) & ~(uintptr_t)15);
    unsigned short* abf = (unsigned short*)p; p += (size_t)n * 128 * 2;

    int chunk = (ne + NB - 1) / NB;
    int nb_g = (n + 63) / 64;
    int nb_a = (n + 3) / 4;

    // CSR build (+fused weight casts in k_hist)
    k_hist<<<NB, 256, 0, stream>>>(dst, hist, W1, W2, Wt1, Wt2, ne, chunk);
    k_scanb<<<1, 256, 0, stream>>>(hist, bstart, row_start, n, ne);
    k_scat<<<NB, 256, 0, stream>>>(src, dst, hist, ebuf, ne, chunk);
    k_bsort<<<256, 256, 0, stream>>>(ebuf, bstart, csr, row_start, dinv, n);

    // conv1 (GEMM reads f32 x directly, writes fp8)
    k_gemm_mfma<true><<<nb_g, 256, 0, stream>>>((const void*)x, (const short*)Wt1, h8, n);
    k_agg<<<nb_a, 256, 0, stream>>>(h8, dinv, csr, row_start, b1, abf, n);

    // conv2
    k_gemm_mfma<false><<<nb_g, 256, 0, stream>>>((const void*)abf, (const short*)Wt2, h8, n);
    k_agg<<<nb_a, 256, 0, stream>>>(h8, dinv, csr, row_start, b2, abf, n);

    // fused pool + head
    k_phead<<<64, 256, 0, stream>>>(abf, batch, Wh1, bh1, Wh2, bh2, out, n);
}

// Round 17
// 180.647 us; speedup vs baseline: 1.4709x; 1.4709x over previous
//
#include <hip/hip_runtime.h>

// ---------------------------------------------------------------------------
// GCN forward, round 12: revert pool+head fusion (R11's k_phead = 115us,
// 64-block serialization — same mistake class as R1 k_scan). Keep R11's
// low-risk wins: packed-shfl agg (1 shfl/edge), castw fused into k_hist.
// Base structure = R10 (182us best).
// ---------------------------------------------------------------------------

#define NB 256    // scatter blocks
#define NBK 256   // buckets (dst>>8; requires n <= 65536)

typedef __attribute__((ext_vector_type(8))) short bf16x8;
typedef __attribute__((ext_vector_type(4))) float f32x4;
typedef __attribute__((ext_vector_type(2))) float f32x2;

__device__ inline unsigned short f2bf(float f) {
    union { float f; unsigned int u; } c; c.f = f;
    unsigned int u = c.u + (0x7fffu + ((c.u >> 16) & 1u));  // RNE
    return (unsigned short)(u >> 16);
}
__device__ inline float bf2f(unsigned short b) {
    union { unsigned int u; float f; } c; c.u = ((unsigned int)b) << 16;
    return c.f;
}
__device__ inline float asf(unsigned int u) {
    union { unsigned int u; float f; } c; c.u = u; return c.f;
}

// Software OCP e4m3fn encode/decode (fallback only).
__device__ inline unsigned char f2fp8_sw(float f) {
    union { float f; unsigned int u; } c; c.f = f;
    unsigned int s = (c.u >> 24) & 0x80u;
    unsigned int au = c.u & 0x7FFFFFFFu;
    if (au >= 0x3C800000u) {
        if (au > 0x43E00000u) au = 0x43E00000u;
        unsigned int r = au + 0x000FFFFFu + ((au >> 20) & 1u);
        unsigned int e8 = (r >> 23) - 120u;
        unsigned int m8 = (r >> 20) & 7u;
        return (unsigned char)(s | (e8 << 3) | m8);
    }
    float av = c.f < 0.f ? -c.f : c.f;
    unsigned int M = (unsigned int)(av * 512.0f + 0.5f);
    return (unsigned char)(s | M);
}
__device__ inline float fp82f_sw(unsigned int cbyte) {
    unsigned int E = (cbyte >> 3) & 0xFu, M = cbyte & 7u;
    union { unsigned int u; float f; } v;
    v.u = ((E + 120u) << 23) | (M << 20);
    float r = E ? v.f : (float)M * 0.001953125f;
    return (cbyte & 0x80u) ? -r : r;
}

// Decode 2 packed fp8 from low (HI=false) or high (HI=true) 16 bits of u.
template <bool HI>
__device__ inline f32x2 fp8x2_f32(unsigned int u) {
#if __has_builtin(__builtin_amdgcn_cvt_pk_f32_fp8)
    return __builtin_amdgcn_cvt_pk_f32_fp8(u, HI);
#else
    unsigned int w = HI ? (u >> 16) : u;
    f32x2 r; r[0] = fp82f_sw(w & 0xFFu); r[1] = fp82f_sw((w >> 8) & 0xFFu);
    return r;
#endif
}
__device__ inline unsigned char f2fp8(float f) {
#if __has_builtin(__builtin_amdgcn_cvt_pk_fp8_f32)
    return (unsigned char)(__builtin_amdgcn_cvt_pk_fp8_f32(f, f, 0, false) & 0xFFu);
#else
    return f2fp8_sw(f);
#endif
}

// kA: per-block bucket histogram; blocks 0..127 also transpose-cast W1/W2;
// also zeroes pool sums/cnt (used later by k_pool).
__global__ __launch_bounds__(256) void k_hist(const int* __restrict__ dst,
                                              int* __restrict__ hist,
                                              const float* __restrict__ W1,
                                              const float* __restrict__ W2,
                                              unsigned short* __restrict__ Wt1,
                                              unsigned short* __restrict__ Wt2,
                                              float* __restrict__ sums,
                                              float* __restrict__ cnt,
                                              int ne, int chunk) {
    __shared__ int h[NBK];
    int t = threadIdx.x, b = blockIdx.x;
    h[t] = 0;
    int gid = b * 256 + t;
    if (b < 64) {                       // Wt1[i] = bf16(W1[kk][nn])
        int i = gid, nn = i >> 7, kk = i & 127;
        Wt1[i] = f2bf(W1[kk * 128 + nn]);
    } else if (b < 128) {
        int i = gid - 16384, nn = i >> 7, kk = i & 127;
        Wt2[i] = f2bf(W2[kk * 128 + nn]);
    }
    if (gid < 64 * 128) sums[gid] = 0.0f;
    if (gid < 64) cnt[gid] = 0.0f;
    __syncthreads();
    int e0 = b * chunk, e1 = min(e0 + chunk, ne);
    for (int e = e0 + t; e < e1; e += 256) atomicAdd(&h[dst[e] >> 8], 1);
    __syncthreads();
    hist[b * NBK + t] = h[t];
}

// kB: single block; thread j owns bucket j. Column-scan over blocks ->
// per-(block,bucket) base (in place), bucket starts, row_start[n] sentinel.
__global__ __launch_bounds__(256) void k_scanb(int* __restrict__ hist,
                                               int* __restrict__ bstart,
                                               int* __restrict__ row_start,
                                               int n, int ne) {
    __shared__ int ps[256];
    int j = threadIdx.x;
    int run = 0;
    for (int i = 0; i < NB; ++i) {
        int t = hist[i * NBK + j];
        hist[i * NBK + j] = run;
        run += t;
    }
    ps[j] = run;
    __syncthreads();
    for (int off = 1; off < 256; off <<= 1) {
        int v = (j >= off) ? ps[j - off] : 0;
        __syncthreads();
        ps[j] += v;
        __syncthreads();
    }
    int excl = ps[j] - run;
    bstart[j] = excl;
    if (j == 255) bstart[256] = ps[255];
    if (j == 0) row_start[n] = ne;
    for (int i = 0; i < NB; ++i) hist[i * NBK + j] += excl;
}

// kC: scatter edges into block-private bucket slices. Pack (dst&255)<<24|src.
__global__ __launch_bounds__(256) void k_scat(const int* __restrict__ src,
                                              const int* __restrict__ dst,
                                              const int* __restrict__ hist,
                                              unsigned int* __restrict__ ebuf,
                                              int ne, int chunk) {
    __shared__ int cur[NBK];
    int t = threadIdx.x, b = blockIdx.x;
    cur[t] = hist[b * NBK + t];
    __syncthreads();
    int e0 = b * chunk, e1 = min(e0 + chunk, ne);
    for (int e = e0 + t; e < e1; e += 256) {
        int d = dst[e];
        int p = atomicAdd(&cur[d >> 8], 1);
        ebuf[p] = ((unsigned int)(d & 255) << 24) | (unsigned int)src[e];
    }
}

// kD: one block per bucket: LDS counting sort -> csr, row_start, dinv.
__global__ __launch_bounds__(256) void k_bsort(const unsigned int* __restrict__ ebuf,
                                               const int* __restrict__ bstart,
                                               int* __restrict__ csr,
                                               int* __restrict__ row_start,
                                               float* __restrict__ dinv,
                                               int n) {
    __shared__ int h[NBK];
    __shared__ int sc[NBK];
    int j = threadIdx.x, b = blockIdx.x;
    int s0 = bstart[b], s1 = bstart[b + 1];
    h[j] = 0;
    __syncthreads();
    for (int e = s0 + j; e < s1; e += 256) atomicAdd(&h[ebuf[e] >> 24], 1);
    __syncthreads();
    sc[j] = h[j];
    __syncthreads();
    for (int off = 1; off < 256; off <<= 1) {
        int v = (j >= off) ? sc[j - off] : 0;
        __syncthreads();
        sc[j] += v;
        __syncthreads();
    }
    int excl = sc[j] - h[j];
    int id = b * 256 + j;
    int deg = h[j];
    if (id < n) {
        row_start[id] = s0 + excl;
        dinv[id] = rsqrtf((float)deg + 1.0f);
    }
    __syncthreads();
    h[j] = excl;
    __syncthreads();
    for (int e = s0 + j; e < s1; e += 256) {
        unsigned int pk = ebuf[e];
        int p = atomicAdd(&h[pk >> 24], 1);
        csr[s0 + p] = (int)(pk & 0x00FFFFFFu);
    }
}

// Y[M x 128](fp8) = X[M x 128] @ W (Wt = W^T bf16 [128][128]).
// F32IN: X f32 (in-register convert); else bf16. 4 waves, 64 rows/block.
template <bool F32IN>
__global__ __launch_bounds__(256) void k_gemm_mfma(const void* __restrict__ Xin,
                                                   const short* __restrict__ Wt,
                                                   unsigned char* __restrict__ Y8,
                                                   int n_rows) {
    int wid = threadIdx.x >> 6;
    int lane = threadIdx.x & 63;
    int r = lane & 15, q = lane >> 4;
    int m0 = blockIdx.x * 64;
    int n0 = wid * 32;

    bf16x8 bfr[2][4];
#pragma unroll
    for (int nt = 0; nt < 2; ++nt)
#pragma unroll
        for (int ks = 0; ks < 4; ++ks)
            bfr[nt][ks] = *(const bf16x8*)(Wt + (size_t)(n0 + nt * 16 + r) * 128 +
                                           ks * 32 + q * 8);

#pragma unroll
    for (int rt = 0; rt < 4; ++rt) {
        int row = m0 + rt * 16 + r;
        int rl = min(row, n_rows - 1);
        f32x4 acc0 = {0.f, 0.f, 0.f, 0.f};
        f32x4 acc1 = {0.f, 0.f, 0.f, 0.f};
#pragma unroll
        for (int ks = 0; ks < 4; ++ks) {
            bf16x8 a;
            if constexpr (F32IN) {
                const float* xr = (const float*)Xin + (size_t)rl * 128 + ks * 32 + q * 8;
                float4 f0 = *(const float4*)xr;
                float4 f1 = *(const float4*)(xr + 4);
                a[0] = (short)f2bf(f0.x); a[1] = (short)f2bf(f0.y);
                a[2] = (short)f2bf(f0.z); a[3] = (short)f2bf(f0.w);
                a[4] = (short)f2bf(f1.x); a[5] = (short)f2bf(f1.y);
                a[6] = (short)f2bf(f1.z); a[7] = (short)f2bf(f1.w);
            } else {
                a = *(const bf16x8*)((const short*)Xin + (size_t)rl * 128 + ks * 32 + q * 8);
            }
            acc0 = __builtin_amdgcn_mfma_f32_16x16x32_bf16(a, bfr[0][ks], acc0, 0, 0, 0);
            acc1 = __builtin_amdgcn_mfma_f32_16x16x32_bf16(a, bfr[1][ks], acc1, 0, 0, 0);
        }
#pragma unroll
        for (int v = 0; v < 4; ++v) {
            int orow = m0 + rt * 16 + q * 4 + v;
            if (orow < n_rows) {
                Y8[(size_t)orow * 128 + n0 + r]      = f2fp8(acc0[v]);
                Y8[(size_t)orow * 128 + n0 + 16 + r] = f2fp8(acc1[v]);
            }
        }
    }
}

// out[d][:] = bf16( relu( sum_e h[src]*w_e + h[d]*di^2 + bias ) )
// h fp8 [n][128]; one wave/node; half-wave dword gather (R10 structure).
// Lane pre-packs (bf16(w)<<16 | src) -> ONE shfl per edge in the hot loop.
__global__ __launch_bounds__(256) void k_agg(const unsigned char* __restrict__ h8,
                                             const float* __restrict__ dinv,
                                             const int* __restrict__ csr,
                                             const int* __restrict__ row_start,
                                             const float* __restrict__ bias,
                                             unsigned short* __restrict__ out,
                                             int n) {
    int node = blockIdx.x * 4 + (threadIdx.x >> 6);
    if (node >= n) return;
    int lane = threadIdx.x & 63;
    int s = lane >> 5, fi = lane & 31;  // half, feature-dword index
    const unsigned int* hp = (const unsigned int*)h8;  // [n][32] dwords

    float di = dinv[node];
    float selfw = (s == 0) ? di * di : 0.0f;
    unsigned int hu = hp[(size_t)node * 32 + fi];
    f32x2 p0 = fp8x2_f32<false>(hu);
    f32x2 p1 = fp8x2_f32<true>(hu);
    float a0 = p0[0] * selfw, a1 = p0[1] * selfw;
    float a2 = p1[0] * selfw, a3 = p1[1] * selfw;

    int beg = row_start[node];
    int end = row_start[node + 1];
    int deg = end - beg;

    int mysrc = (lane < deg) ? csr[beg + lane] : 0;
    float myw = ((lane < deg) ? dinv[mysrc] : 0.0f) * di;
    // pack: bf16 weight in high 16, src id (<65536) in low 16
    unsigned int mypk = ((unsigned int)f2bf(myw) << 16) | (unsigned int)(mysrc & 0xFFFF);

    int m = min(deg, 64);
    int e = 0;
    for (; e + 8 <= m; e += 8) {  // halves s=0/1 -> edges e+s, e+2+s, ...
        unsigned int k0 = __shfl(mypk, e + s);
        unsigned int k1 = __shfl(mypk, e + 2 + s);
        unsigned int k2 = __shfl(mypk, e + 4 + s);
        unsigned int k3 = __shfl(mypk, e + 6 + s);
        unsigned int u0 = hp[(size_t)(k0 & 0xFFFFu) * 32 + fi];
        unsigned int u1 = hp[(size_t)(k1 & 0xFFFFu) * 32 + fi];
        unsigned int u2 = hp[(size_t)(k2 & 0xFFFFu) * 32 + fi];
        unsigned int u3 = hp[(size_t)(k3 & 0xFFFFu) * 32 + fi];
        float w0 = asf(k0 & 0xFFFF0000u);
        float w1 = asf(k1 & 0xFFFF0000u);
        float w2 = asf(k2 & 0xFFFF0000u);
        float w3 = asf(k3 & 0xFFFF0000u);
        f32x2 v;
        v = fp8x2_f32<false>(u0); a0 += v[0] * w0; a1 += v[1] * w0;
        v = fp8x2_f32<true>(u0);  a2 += v[0] * w0; a3 += v[1] * w0;
        v = fp8x2_f32<false>(u1); a0 += v[0] * w1; a1 += v[1] * w1;
        v = fp8x2_f32<true>(u1);  a2 += v[0] * w1; a3 += v[1] * w1;
        v = fp8x2_f32<false>(u2); a0 += v[0] * w2; a1 += v[1] * w2;
        v = fp8x2_f32<true>(u2);  a2 += v[0] * w2; a3 += v[1] * w2;
        v = fp8x2_f32<false>(u3); a0 += v[0] * w3; a1 += v[1] * w3;
        v = fp8x2_f32<true>(u3);  a2 += v[0] * w3; a3 += v[1] * w3;
    }
    for (; e < m; e += 2) {  // guarded tail, 2 edges/iter
        int idx = e + s;
        unsigned int k = __shfl(mypk, idx & 63);
        float w = asf(k & 0xFFFF0000u);
        if (idx >= m) w = 0.0f;
        unsigned int u = hp[(size_t)(k & 0xFFFFu) * 32 + fi];
        f32x2 v;
        v = fp8x2_f32<false>(u); a0 += v[0] * w; a1 += v[1] * w;
        v = fp8x2_f32<true>(u);  a2 += v[0] * w; a3 += v[1] * w;
    }
    if (s == 0) {  // rare deg>64 overflow: half 0 serial
        for (int j = beg + 64; j < end; ++j) {
            int sx = csr[j];
            float w = dinv[sx] * di;
            unsigned int u = hp[(size_t)sx * 32 + fi];
            f32x2 v;
            v = fp8x2_f32<false>(u); a0 += v[0] * w; a1 += v[1] * w;
            v = fp8x2_f32<true>(u);  a2 += v[0] * w; a3 += v[1] * w;
        }
    }

    // cross-half reduce
    a0 += __shfl_xor(a0, 32);
    a1 += __shfl_xor(a1, 32);
    a2 += __shfl_xor(a2, 32);
    a3 += __shfl_xor(a3, 32);

    if (s == 0) {
        float4 bv = ((const float4*)bias)[fi];
        float o0 = fmaxf(a0 + bv.x, 0.0f);
        float o1 = fmaxf(a1 + bv.y, 0.0f);
        float o2 = fmaxf(a2 + bv.z, 0.0f);
        float o3 = fmaxf(a3 + bv.w, 0.0f);
        uint2 pk;
        pk.x = (unsigned int)f2bf(o0) | ((unsigned int)f2bf(o1) << 16);
        pk.y = (unsigned int)f2bf(o2) | ((unsigned int)f2bf(o3) << 16);
        *(uint2*)(out + (size_t)node * 128 + fi * 4) = pk;
    }
}

// Segmented mean-pool over sorted batch; h is bf16. (R10 structure, 782 blocks)
#define POOL_CHUNK 64
__global__ __launch_bounds__(128) void k_pool(const unsigned short* __restrict__ h,
                                              const int* __restrict__ batch,
                                              float* __restrict__ sums,
                                              float* __restrict__ cnt, int n) {
    int d = threadIdx.x;
    int c0 = blockIdx.x * POOL_CHUNK;
    if (c0 >= n) return;
    int c1 = min(c0 + POOL_CHUNK, n);
    float acc = 0.f, cc = 0.f;
    int g_cur = batch[c0];
    for (int i = c0; i < c1; ++i) {
        int g = batch[i];
        if (g != g_cur) {
            atomicAdd(&sums[g_cur * 128 + d], acc);
            if (d == 0) atomicAdd(&cnt[g_cur], cc);
            acc = 0.f; cc = 0.f; g_cur = g;
        }
        acc += bf2f(h[(size_t)i * 128 + d]);
        cc += 1.f;
    }
    atomicAdd(&sums[g_cur * 128 + d], acc);
    if (d == 0) atomicAdd(&cnt[g_cur], cc);
}

// One block per graph: pooled mean -> Linear+ReLU -> dot+sigmoid.
__global__ __launch_bounds__(128) void k_head(const float* __restrict__ sums,
                                              const float* __restrict__ cnt,
                                              const float* __restrict__ Wh1,
                                              const float* __restrict__ bh1,
                                              const float* __restrict__ Wh2,
                                              const float* __restrict__ bh2,
                                              float* __restrict__ out) {
    int g = blockIdx.x;
    int d = threadIdx.x;
    __shared__ float sp[128];
    __shared__ float red[128];
    float c = fmaxf(cnt[g], 1.0f);
    sp[d] = sums[g * 128 + d] / c;
    __syncthreads();
    float acc = bh1[d];
    for (int k = 0; k < 128; ++k) acc += sp[k] * Wh1[k * 128 + d];
    float z = fmaxf(acc, 0.f);
    red[d] = z * Wh2[d];
    __syncthreads();
    for (int off = 64; off > 0; off >>= 1) {
        if (d < off) red[d] += red[d + off];
        __syncthreads();
    }
    if (d == 0) out[g] = 1.f / (1.f + expf(-(red[0] + bh2[0])));
}

extern "C" void kernel_launch(void* const* d_in, const int* in_sizes, int n_in,
                              void* d_out, int out_size, void* d_ws,
                              size_t ws_size, hipStream_t stream) {
    const float* x    = (const float*)d_in[0];
    const int*   ei   = (const int*)d_in[1];
    const int*   batch= (const int*)d_in[2];
    const float* W1   = (const float*)d_in[3];
    const float* b1   = (const float*)d_in[4];
    const float* W2   = (const float*)d_in[5];
    const float* b2   = (const float*)d_in[6];
    const float* Wh1  = (const float*)d_in[7];
    const float* bh1  = (const float*)d_in[8];
    const float* Wh2  = (const float*)d_in[9];
    const float* bh2  = (const float*)d_in[10];
    float* out = (float*)d_out;

    const int n  = in_sizes[0] / 128;  // 50000
    const int ne = in_sizes[1] / 2;    // 800000
    const int* src = ei;
    const int* dst = ei + ne;

    char* p = (char*)d_ws;
    int* hist      = (int*)p;  p += (size_t)NB * NBK * 4;
    int* bstart    = (int*)p;  p += 257 * 4;
    int* row_start = (int*)p;  p += (size_t)(n + 1) * 4;
    float* dinv    = (float*)p; p += (size_t)n * 4;
    unsigned int* ebuf = (unsigned int*)p; p += (size_t)ne * 4;
    int* csr       = (int*)p;  p += (size_t)ne * 4;
    p = (char*)(((uintptr_t)p + 15) & ~(uintptr_t)15);
    unsigned short* Wt1 = (unsigned short*)p; p += 128 * 128 * 2;
    unsigned short* Wt2 = (unsigned short*)p; p += 128 * 128 * 2;
    unsigned char* h8   = (unsigned char*)p; p += (size_t)n * 128;
    p = (char*)(((uintptr_t)p + 15) & ~(uintptr_t)15);
    unsigned short* abf = (unsigned short*)p; p += (size_t)n * 128 * 2;
    p = (char*)(((uintptr_t)p + 15) & ~(uintptr_t)15);
    float* sums = (float*)p;   p += (size_t)64 * 128 * 4;
    float* cnt  = (float*)p;

    int chunk = (ne + NB - 1) / NB;
    int nb_g = (n + 63) / 64;
    int nb_a = (n + 3) / 4;
    int nb_p = (n + POOL_CHUNK - 1) / POOL_CHUNK;

    // CSR build (+fused weight casts & pool-buffer zeroing in k_hist)
    k_hist<<<NB, 256, 0, stream>>>(dst, hist, W1, W2, Wt1, Wt2, sums, cnt, ne, chunk);
    k_scanb<<<1, 256, 0, stream>>>(hist, bstart, row_start, n, ne);
    k_scat<<<NB, 256, 0, stream>>>(src, dst, hist, ebuf, ne, chunk);
    k_bsort<<<256, 256, 0, stream>>>(ebuf, bstart, csr, row_start, dinv, n);

    // conv1 (GEMM reads f32 x directly, writes fp8)
    k_gemm_mfma<true><<<nb_g, 256, 0, stream>>>((const void*)x, (const short*)Wt1, h8, n);
    k_agg<<<nb_a, 256, 0, stream>>>(h8, dinv, csr, row_start, b1, abf, n);

    // conv2
    k_gemm_mfma<false><<<nb_g, 256, 0, stream>>>((const void*)abf, (const short*)Wt2, h8, n);
    k_agg<<<nb_a, 256, 0, stream>>>(h8, dinv, csr, row_start, b2, abf, n);

    // pool + head (R10 structure)
    k_pool<<<nb_p, 128, 0, stream>>>(abf, batch, sums, cnt, n);
    k_head<<<64, 128, 0, stream>>>(sums, cnt, Wh1, bh1, Wh2, bh2, out);
}